// Round 4
// baseline (210.524 us; speedup 1.0000x reference)
//
#include <hip/hip_runtime.h>
#include <cstdint>

#define B 16
#define H 128
#define W 128
#define NC 80
#define PB (H*W*NC)
#define K 100
#define NSUB 16          // sub-counters per batch (atomic distribution)
#define SEGCAP 1024      // candidate slots per (batch, sub)
#define THRESH 0.95f
#define NBINS 4096
#define LISTCAP 512
#define LBUF 256         // per-block LDS candidate buffer (exp ~26/block)
#define TY 16            // output rows per wave-tile
#define OX 14            // output cols per wave-tile (16 loaded, 14 emitted)
#define YT (H/TY)        // 8
#define XT 10            // ceil(W/OX)
#define NBLK (B*YT*XT)   // 1280
#define BPB (YT*XT)      // blocks per batch = 80

__device__ unsigned long long g_cand[B * NSUB * SEGCAP];   // 2 MB
__device__ int g_counts[B * NSUB * 16] = {};  // 64B-strided; zeroed at load; topk re-zeros
__device__ int g_arrive[B] = {};              // per-batch arrival counters; topk re-zeros

__device__ __forceinline__ float sigmoidf(float x) {
    return 1.0f / (1.0f + expf(-x));
}
__device__ __forceinline__ float4 f4max2(float4 a, float4 b) {
    float4 r;
    r.x = fmaxf(a.x, b.x); r.y = fmaxf(a.y, b.y);
    r.z = fmaxf(a.z, b.z); r.w = fmaxf(a.w, b.w);
    return r;
}
__device__ __forceinline__ float4 shfl4(float4 v, int src) {
    float4 r;
    r.x = __shfl(v.x, src);
    r.y = __shfl(v.y, src);
    r.z = __shfl(v.z, src);
    r.w = __shfl(v.w, src);
    return r;
}

// Fused kernel (round 4 == round 3 resubmit; round-3 bench was an infra
// failure, not a kernel failure — identical source, same prediction).
// Round-1: LDS 24KB made the backend chase ~8 waves/EU -> 28 VGPR -> spilled
// pipeline (115us). Round-2: waves_per_eu(2,2) restored 88 VGPR but the max=2
// cap left 1 block/CU resident (occupancy 8.8%, 5 serialized rounds, 110us).
// Round-3/4: waves_per_eu(2,5) -> regalloc target 5 waves/EU (budget ~102
// VGPR, kernel needs ~88, no spill; relaxes toward min=2 before spilling)
// while runtime residency rises to 4 blocks/CU (20 waves/CU).
__global__ void
__attribute__((amdgpu_flat_work_group_size(320, 320)))
__attribute__((amdgpu_waves_per_eu(2, 5)))
fused_kernel(const float* __restrict__ cls,
             const float* __restrict__ dxy,
             const float* __restrict__ swh,
             float* __restrict__ out) {
    const int raw = blockIdx.x;                          // 1280
    const int blk = (raw & 7) * (NBLK / 8) + (raw >> 3); // XCD-contiguous ranges
    const int b   = blk / (YT * XT);
    const int rem = blk - b * (YT * XT);
    const int yt  = rem / XT;
    const int xt  = rem - yt * XT;
    const int sub = rem & (NSUB - 1);                    // 16-way atomic distribution
    const int tid  = threadIdx.x;
    const int lane = tid & 63;
    const int cg   = tid >> 6;                           // class group 0..4
    const int c4   = lane & 3;
    const int xl   = lane >> 2;                          // 0..15
    const int xg   = xt * OX - 1 + xl;                   // global col, may be OOB
    const int y0   = yt * TY;
    const int cbase = cg * 16 + c4 * 4;

    __shared__ unsigned long long lbuf[LBUF];
    __shared__ int lcnt;
    __shared__ int sbase;
    __shared__ int lastflag;
    if (tid == 0) lcnt = 0;
    __syncthreads();

    int* const cnt_p = &g_counts[(b * NSUB + sub) * 16];
    unsigned long long* const seg_p = &g_cand[(size_t)(b * NSUB + sub) * SEGCAP];

    const float NI = -__builtin_inff();
    const float4 NEG = make_float4(NI, NI, NI, NI);
    const float* bp = cls + (size_t)b * PB + cbase;

    const bool xv = (xg >= 0) & (xg < W);
    const bool emitOK = (xl >= 1) & (xl <= OX) & (xg < W);

    const int lsrcL = (lane - 4) & 63;
    const int lsrcR = (lane + 4) & 63;

    auto ld = [&](int j) -> float4 {                     // raw row j (y = y0-1+j)
        const int y = y0 - 1 + j;
        const bool ok = (y >= 0) & (y < H) & xv;
        return ok ? *(const float4*)(bp + (size_t)(y * W + xg) * NC) : NEG;
    };

    // 8 named slots; rows 0..6 preloaded -> 7 loads in flight steady-state.
    float4 w0 = ld(0), w1 = ld(1), w2 = ld(2), w3 = ld(3);
    float4 w4 = ld(4), w5 = ld(5), w6 = ld(6), w7;

    float4 pair = f4max2(w0, w1);                        // max(rows k, k+1)

    auto step = [&](const float4& ctr, const float4& bot, float4& fre, int k) {
        if (k + 7 <= TY + 1) fre = ld(k + 7);            // prefetch row k+7
        float4 v3 = f4max2(pair, bot);                   // vertical 3-max, own col
        float cmax = fmaxf(fmaxf(ctr.x, ctr.y), fmaxf(ctr.z, ctr.w));
        const bool pre = emitOK & (cmax > 2.9f);         // candidate needs own v>2.9
        if (__any(pre)) {                                // wave-uniform skip
            float4 Lv = shfl4(v3, lsrcL);
            float4 Rv = shfl4(v3, lsrcR);
            float4 vm4 = f4max2(f4max2(Lv, Rv), v3);     // full 3x3 max (exact)
            if (pre) {
                const int yo = y0 + k;
                float vv[4] = { ctr.x, ctr.y, ctr.z, ctr.w };
                float mm[4] = { vm4.x, vm4.y, vm4.z, vm4.w };
                #pragma unroll
                for (int c = 0; c < 4; ++c) {
                    float v = vv[c], vm = mm[c];
                    // logit prefilter band 1e-3 >> worst-case sigmoid
                    // rounding-collision window (~1.5e-5)
                    if (v > 2.9f && (vm - v) <= 1e-3f) {
                        float sc = sigmoidf(v);
                        float sm = sigmoidf(vm);         // monotone: = max sigmoid
                        if (sc == sm && sc > THRESH) {
                            unsigned ib = ((unsigned)(yo * W + xg)) * NC + cbase + c;
                            unsigned long long key =
                                ((unsigned long long)__float_as_uint(sc) << 32) |
                                (unsigned long long)(0xFFFFFFFFu - ib);
                            int p = atomicAdd(&lcnt, 1);     // LDS atomic (lgkm)
                            if (p < LBUF) lbuf[p] = key;     // LDS write (lgkm)
                        }
                    }
                }
            }
        }
        pair = f4max2(ctr, bot);                         // pair for next step
    };

    // step k: ctr=row k+1 (slot (k+1)&7), bot=row k+2, fill slot (k+7)&7.
    step(w1, w2, w7, 0);   step(w2, w3, w0, 1);   step(w3, w4, w1, 2);
    step(w4, w5, w2, 3);   step(w5, w6, w3, 4);   step(w6, w7, w4, 5);
    step(w7, w0, w5, 6);   step(w0, w1, w6, 7);   step(w1, w2, w7, 8);
    step(w2, w3, w0, 9);   step(w3, w4, w1, 10);  step(w4, w5, w2, 11);
    step(w5, w6, w3, 12);  step(w6, w7, w4, 13);  step(w7, w0, w5, 14);
    step(w0, w1, w6, 15);

    // ---- block flush: ONE global atomic, then coalesced agent-scope stores ----
    __syncthreads();
    int m = lcnt < LBUF ? lcnt : LBUF;
    if (tid == 0 && m > 0) sbase = atomicAdd(cnt_p, m);
    __syncthreads();
    for (int i = tid; i < m; i += 320) {
        int slot = sbase + i;
        if (slot < SEGCAP)
            __hip_atomic_store(&seg_p[slot], lbuf[i],
                               __ATOMIC_RELAXED, __HIP_MEMORY_SCOPE_AGENT);
    }

    // ---- arrival: last block of this batch runs stage B ----
    // __syncthreads drains vmcnt(0): all agent-scope stores are at the
    // coherence point before the release add below.
    __syncthreads();
    if (tid == 0) {
        int prev = __hip_atomic_fetch_add(&g_arrive[b], 1,
                                          __ATOMIC_ACQ_REL, __HIP_MEMORY_SCOPE_AGENT);
        lastflag = (prev == BPB - 1);
    }
    __syncthreads();
    if (!lastflag) return;

    // ================= Stage B: exact top-K for batch b =================
    __shared__ int hist[NBINS];
    __shared__ int csum[256];
    __shared__ int segn[NSUB];
    __shared__ unsigned long long list[LISTCAP];
    __shared__ int lcount;
    __shared__ int kstar;

    if (tid < NSUB) {
        int n = __hip_atomic_load(&g_counts[(b * NSUB + tid) * 16],
                                  __ATOMIC_RELAXED, __HIP_MEMORY_SCOPE_AGENT);
        segn[tid] = n > SEGCAP ? SEGCAP : n;
    }
    for (int i = tid; i < NBINS; i += 320) hist[i] = 0;
    if (tid == 0) lcount = 0;
    __syncthreads();

    const float SCALE = (float)NBINS / (1.0f - THRESH);
    #pragma unroll 1
    for (int s = 0; s < NSUB; ++s) {
        unsigned long long* cb = g_cand + (size_t)(b * NSUB + s) * SEGCAP;
        const int n = segn[s];
        for (int i = tid; i < n; i += 320) {
            unsigned long long key = __hip_atomic_load(&cb[i],
                                     __ATOMIC_RELAXED, __HIP_MEMORY_SCOPE_AGENT);
            float v = __uint_as_float((unsigned)(key >> 32));
            int bin = (int)((v - THRESH) * SCALE);
            bin = bin < 0 ? 0 : (bin > NBINS - 1 ? NBINS - 1 : bin);
            atomicAdd(&hist[bin], 1);
        }
    }
    __syncthreads();

    if (tid < 256) {
        int s0 = 0;
        for (int j = 0; j < NBINS / 256; j++) s0 += hist[tid * (NBINS / 256) + j];
        csum[tid] = s0;
    }
    __syncthreads();

    if (tid == 0) {
        int acc = 0;
        int chunk = 255;
        for (; chunk >= 0; chunk--) {
            if (acc + csum[chunk] >= K) break;
            acc += csum[chunk];
        }
        int ks = 0;
        if (chunk >= 0) {
            int j = NBINS / 256 - 1;
            for (; j >= 0; j--) {
                acc += hist[chunk * (NBINS / 256) + j];
                if (acc >= K) break;
            }
            if (j < 0) j = 0;
            ks = chunk * (NBINS / 256) + j;
        }
        kstar = ks;
    }
    __syncthreads();

    const int ks = kstar;
    #pragma unroll 1
    for (int s = 0; s < NSUB; ++s) {
        unsigned long long* cb = g_cand + (size_t)(b * NSUB + s) * SEGCAP;
        const int n = segn[s];
        for (int i = tid; i < n; i += 320) {
            unsigned long long key = __hip_atomic_load(&cb[i],
                                     __ATOMIC_RELAXED, __HIP_MEMORY_SCOPE_AGENT);
            float v = __uint_as_float((unsigned)(key >> 32));
            int bin = (int)((v - THRESH) * SCALE);
            bin = bin < 0 ? 0 : (bin > NBINS - 1 ? NBINS - 1 : bin);
            if (bin >= ks) {
                int p = atomicAdd(&lcount, 1);
                if (p < LISTCAP) list[p] = key;
            }
        }
    }
    __syncthreads();
    const int M = lcount < LISTCAP ? lcount : LISTCAP;

    // exact rank by counting (keys distinct: low 32 bits unique per batch)
    for (int i = tid; i < M; i += 320) {
        unsigned long long key = list[i];
        int rank = 0;
        for (int j = 0; j < M; j++) rank += (list[j] > key);
        if (rank < K) {
            float conf = __uint_as_float((unsigned)(key >> 32));
            unsigned ib = 0xFFFFFFFFu - (unsigned)(key & 0xFFFFFFFFu);
            unsigned cls_i = ib % (unsigned)NC;
            unsigned sidx = ib / (unsigned)NC;
            unsigned xq = sidx & (W - 1);
            unsigned yq = sidx >> 7;

            size_t goff = ((size_t)b * (H * W) + sidx) * 2;
            float dx = dxy[goff], dy = dxy[goff + 1];
            float sw = swh[goff], sh = swh[goff + 1];

            float xs = (float)xq + dx;
            float ys = (float)yq + dy;
            float hw = sw * 0.5f;
            float hh = sh * 0.5f;
            const float invW = 1.0f / (float)W;
            const float invH = 1.0f / (float)H;

            int r = b * K + rank;
            out[r * 4 + 0] = (xs - hw) * invW;
            out[r * 4 + 1] = (ys - hh) * invH;
            out[r * 4 + 2] = (xs + hw) * invW;
            out[r * 4 + 3] = (ys + hh) * invH;
            out[B * K * 4 + r] = conf;
            out[B * K * 4 + B * K + r] = (float)cls_i;
        }
    }

    __syncthreads();
    // reset persistent state for the next call (launch boundary = coherence)
    if (tid < NSUB)
        __hip_atomic_store(&g_counts[(b * NSUB + tid) * 16], 0,
                           __ATOMIC_RELAXED, __HIP_MEMORY_SCOPE_AGENT);
    if (tid == 0)
        __hip_atomic_store(&g_arrive[b], 0,
                           __ATOMIC_RELAXED, __HIP_MEMORY_SCOPE_AGENT);
}

extern "C" void kernel_launch(void* const* d_in, const int* in_sizes, int n_in,
                              void* d_out, int out_size, void* d_ws, size_t ws_size,
                              hipStream_t stream) {
    const float* cls = (const float*)d_in[0];
    const float* dxy = (const float*)d_in[1];
    const float* swh = (const float*)d_in[2];
    float* out = (float*)d_out;

    fused_kernel<<<NBLK, 320, 0, stream>>>(cls, dxy, swh, out);
}

// Round 5
// 207.087 us; speedup vs baseline: 1.0166x; 1.0166x over previous
//
#include <hip/hip_runtime.h>
#include <cstdint>

#define B 16
#define H 128
#define W 128
#define NC 80
#define PB (H*W*NC)
#define K 100
#define NSUB 16          // sub-counters per batch (atomic distribution)
#define SEGCAP 1024      // candidate slots per (batch, sub)
#define THRESH 0.95f
#define NBINS 4096
#define LISTCAP 512
#define LBUF 256         // per-block LDS candidate buffer (exp ~26/block)
#define TY 16            // output rows per wave-tile
#define OX 14            // output cols per wave-tile (16 loaded, 14 emitted)
#define YT (H/TY)        // 8
#define XT 10            // ceil(W/OX)
#define NBLK (B*YT*XT)   // 1280
#define BPB (YT*XT)      // blocks per batch = 80

__device__ unsigned long long g_cand[B * NSUB * SEGCAP];   // 2 MB
__device__ int g_counts[B * NSUB * 16] = {};  // 64B-strided; zeroed at load; topk re-zeros
__device__ int g_arrive[B] = {};              // per-batch arrival counters; topk re-zeros

__device__ __forceinline__ float sigmoidf(float x) {
    return 1.0f / (1.0f + expf(-x));
}
__device__ __forceinline__ float4 f4max2(float4 a, float4 b) {
    float4 r;
    r.x = fmaxf(a.x, b.x); r.y = fmaxf(a.y, b.y);
    r.z = fmaxf(a.z, b.z); r.w = fmaxf(a.w, b.w);
    return r;
}
__device__ __forceinline__ float4 shfl4(float4 v, int src) {
    float4 r;
    r.x = __shfl(v.x, src);
    r.y = __shfl(v.y, src);
    r.z = __shfl(v.z, src);
    r.w = __shfl(v.w, src);
    return r;
}

// ===== Stage B, OUTLINED (round 5) =====
// Rounds 1-4 showed that having this code inline in the kernel flips the
// backend's scheduler into pressure-reduction mode for the stage-A hot loop
// (VGPR 28/44, pipeline sunk, 110-115us). No waves_per_eu setting decouples
// "relaxed scheduling" from "runtime residency". A __noinline__ call gives
// stage B its own regalloc/scheduling context; no stage-A value is live
// across the call, so the kernel body schedules exactly like round-0's
// proven peak_kernel. __shared__ arrays move into the callee (module-LDS
// lowering still allocates them in the kernel's 24KB frame).
__device__ __noinline__ void topk_stage(int b, int tid,
                                        const float* __restrict__ dxy,
                                        const float* __restrict__ swh,
                                        float* __restrict__ out) {
    __shared__ int hist[NBINS];
    __shared__ int csum[256];
    __shared__ int segn[NSUB];
    __shared__ unsigned long long list[LISTCAP];
    __shared__ int lcount;
    __shared__ int kstar;

    if (tid < NSUB) {
        int n = __hip_atomic_load(&g_counts[(b * NSUB + tid) * 16],
                                  __ATOMIC_RELAXED, __HIP_MEMORY_SCOPE_AGENT);
        segn[tid] = n > SEGCAP ? SEGCAP : n;
    }
    for (int i = tid; i < NBINS; i += 320) hist[i] = 0;
    if (tid == 0) lcount = 0;
    __syncthreads();

    const float SCALE = (float)NBINS / (1.0f - THRESH);
    #pragma unroll 1
    for (int s = 0; s < NSUB; ++s) {
        unsigned long long* cb = g_cand + (size_t)(b * NSUB + s) * SEGCAP;
        const int n = segn[s];
        for (int i = tid; i < n; i += 320) {
            unsigned long long key = __hip_atomic_load(&cb[i],
                                     __ATOMIC_RELAXED, __HIP_MEMORY_SCOPE_AGENT);
            float v = __uint_as_float((unsigned)(key >> 32));
            int bin = (int)((v - THRESH) * SCALE);
            bin = bin < 0 ? 0 : (bin > NBINS - 1 ? NBINS - 1 : bin);
            atomicAdd(&hist[bin], 1);
        }
    }
    __syncthreads();

    if (tid < 256) {
        int s0 = 0;
        for (int j = 0; j < NBINS / 256; j++) s0 += hist[tid * (NBINS / 256) + j];
        csum[tid] = s0;
    }
    __syncthreads();

    if (tid == 0) {
        int acc = 0;
        int chunk = 255;
        for (; chunk >= 0; chunk--) {
            if (acc + csum[chunk] >= K) break;
            acc += csum[chunk];
        }
        int ks = 0;
        if (chunk >= 0) {
            int j = NBINS / 256 - 1;
            for (; j >= 0; j--) {
                acc += hist[chunk * (NBINS / 256) + j];
                if (acc >= K) break;
            }
            if (j < 0) j = 0;
            ks = chunk * (NBINS / 256) + j;
        }
        kstar = ks;
    }
    __syncthreads();

    const int ks = kstar;
    #pragma unroll 1
    for (int s = 0; s < NSUB; ++s) {
        unsigned long long* cb = g_cand + (size_t)(b * NSUB + s) * SEGCAP;
        const int n = segn[s];
        for (int i = tid; i < n; i += 320) {
            unsigned long long key = __hip_atomic_load(&cb[i],
                                     __ATOMIC_RELAXED, __HIP_MEMORY_SCOPE_AGENT);
            float v = __uint_as_float((unsigned)(key >> 32));
            int bin = (int)((v - THRESH) * SCALE);
            bin = bin < 0 ? 0 : (bin > NBINS - 1 ? NBINS - 1 : bin);
            if (bin >= ks) {
                int p = atomicAdd(&lcount, 1);
                if (p < LISTCAP) list[p] = key;
            }
        }
    }
    __syncthreads();
    const int M = lcount < LISTCAP ? lcount : LISTCAP;

    // exact rank by counting (keys distinct: low 32 bits unique per batch)
    for (int i = tid; i < M; i += 320) {
        unsigned long long key = list[i];
        int rank = 0;
        for (int j = 0; j < M; j++) rank += (list[j] > key);
        if (rank < K) {
            float conf = __uint_as_float((unsigned)(key >> 32));
            unsigned ib = 0xFFFFFFFFu - (unsigned)(key & 0xFFFFFFFFu);
            unsigned cls_i = ib % (unsigned)NC;
            unsigned sidx = ib / (unsigned)NC;
            unsigned xq = sidx & (W - 1);
            unsigned yq = sidx >> 7;

            size_t goff = ((size_t)b * (H * W) + sidx) * 2;
            float dx = dxy[goff], dy = dxy[goff + 1];
            float sw = swh[goff], sh = swh[goff + 1];

            float xs = (float)xq + dx;
            float ys = (float)yq + dy;
            float hw = sw * 0.5f;
            float hh = sh * 0.5f;
            const float invW = 1.0f / (float)W;
            const float invH = 1.0f / (float)H;

            int r = b * K + rank;
            out[r * 4 + 0] = (xs - hw) * invW;
            out[r * 4 + 1] = (ys - hh) * invH;
            out[r * 4 + 2] = (xs + hw) * invW;
            out[r * 4 + 3] = (ys + hh) * invH;
            out[B * K * 4 + r] = conf;
            out[B * K * 4 + B * K + r] = (float)cls_i;
        }
    }

    __syncthreads();
    // reset persistent state for the next call (launch boundary = coherence)
    if (tid < NSUB)
        __hip_atomic_store(&g_counts[(b * NSUB + tid) * 16], 0,
                           __ATOMIC_RELAXED, __HIP_MEMORY_SCOPE_AGENT);
    if (tid == 0)
        __hip_atomic_store(&g_arrive[b], 0,
                           __ATOMIC_RELAXED, __HIP_MEMORY_SCOPE_AGENT);
}

// ===== Fused kernel: stage A identical to round-0 peak_kernel =====
__global__ __launch_bounds__(320, 2) void fused_kernel(const float* __restrict__ cls,
                                                       const float* __restrict__ dxy,
                                                       const float* __restrict__ swh,
                                                       float* __restrict__ out) {
    const int raw = blockIdx.x;                          // 1280
    const int blk = (raw & 7) * (NBLK / 8) + (raw >> 3); // XCD-contiguous ranges
    const int b   = blk / (YT * XT);
    const int rem = blk - b * (YT * XT);
    const int yt  = rem / XT;
    const int xt  = rem - yt * XT;
    const int sub = rem & (NSUB - 1);                    // 16-way atomic distribution
    const int tid  = threadIdx.x;
    const int lane = tid & 63;
    const int cg   = tid >> 6;                           // class group 0..4
    const int c4   = lane & 3;
    const int xl   = lane >> 2;                          // 0..15
    const int xg   = xt * OX - 1 + xl;                   // global col, may be OOB
    const int y0   = yt * TY;
    const int cbase = cg * 16 + c4 * 4;

    __shared__ unsigned long long lbuf[LBUF];
    __shared__ int lcnt;
    __shared__ int sbase;
    __shared__ int lastflag;
    if (tid == 0) lcnt = 0;
    __syncthreads();

    int* const cnt_p = &g_counts[(b * NSUB + sub) * 16];
    unsigned long long* const seg_p = &g_cand[(size_t)(b * NSUB + sub) * SEGCAP];

    const float NI = -__builtin_inff();
    const float4 NEG = make_float4(NI, NI, NI, NI);
    const float* bp = cls + (size_t)b * PB + cbase;

    const bool xv = (xg >= 0) & (xg < W);
    const bool emitOK = (xl >= 1) & (xl <= OX) & (xg < W);

    const int lsrcL = (lane - 4) & 63;
    const int lsrcR = (lane + 4) & 63;

    auto ld = [&](int j) -> float4 {                     // raw row j (y = y0-1+j)
        const int y = y0 - 1 + j;
        const bool ok = (y >= 0) & (y < H) & xv;
        return ok ? *(const float4*)(bp + (size_t)(y * W + xg) * NC) : NEG;
    };

    // 8 named slots; rows 0..6 preloaded -> 7 loads in flight steady-state.
    float4 w0 = ld(0), w1 = ld(1), w2 = ld(2), w3 = ld(3);
    float4 w4 = ld(4), w5 = ld(5), w6 = ld(6), w7;

    float4 pair = f4max2(w0, w1);                        // max(rows k, k+1)

    auto step = [&](const float4& ctr, const float4& bot, float4& fre, int k) {
        if (k + 7 <= TY + 1) fre = ld(k + 7);            // prefetch row k+7
        float4 v3 = f4max2(pair, bot);                   // vertical 3-max, own col
        float cmax = fmaxf(fmaxf(ctr.x, ctr.y), fmaxf(ctr.z, ctr.w));
        const bool pre = emitOK & (cmax > 2.9f);         // candidate needs own v>2.9
        if (__any(pre)) {                                // wave-uniform skip
            float4 Lv = shfl4(v3, lsrcL);
            float4 Rv = shfl4(v3, lsrcR);
            float4 vm4 = f4max2(f4max2(Lv, Rv), v3);     // full 3x3 max (exact)
            if (pre) {
                const int yo = y0 + k;
                float vv[4] = { ctr.x, ctr.y, ctr.z, ctr.w };
                float mm[4] = { vm4.x, vm4.y, vm4.z, vm4.w };
                #pragma unroll
                for (int c = 0; c < 4; ++c) {
                    float v = vv[c], vm = mm[c];
                    // logit prefilter band 1e-3 >> worst-case sigmoid
                    // rounding-collision window (~1.5e-5)
                    if (v > 2.9f && (vm - v) <= 1e-3f) {
                        float sc = sigmoidf(v);
                        float sm = sigmoidf(vm);         // monotone: = max sigmoid
                        if (sc == sm && sc > THRESH) {
                            unsigned ib = ((unsigned)(yo * W + xg)) * NC + cbase + c;
                            unsigned long long key =
                                ((unsigned long long)__float_as_uint(sc) << 32) |
                                (unsigned long long)(0xFFFFFFFFu - ib);
                            int p = atomicAdd(&lcnt, 1);     // LDS atomic (lgkm)
                            if (p < LBUF) lbuf[p] = key;     // LDS write (lgkm)
                        }
                    }
                }
            }
        }
        pair = f4max2(ctr, bot);                         // pair for next step
    };

    // step k: ctr=row k+1 (slot (k+1)&7), bot=row k+2, fill slot (k+7)&7.
    step(w1, w2, w7, 0);   step(w2, w3, w0, 1);   step(w3, w4, w1, 2);
    step(w4, w5, w2, 3);   step(w5, w6, w3, 4);   step(w6, w7, w4, 5);
    step(w7, w0, w5, 6);   step(w0, w1, w6, 7);   step(w1, w2, w7, 8);
    step(w2, w3, w0, 9);   step(w3, w4, w1, 10);  step(w4, w5, w2, 11);
    step(w5, w6, w3, 12);  step(w6, w7, w4, 13);  step(w7, w0, w5, 14);
    step(w0, w1, w6, 15);

    // ---- block flush: ONE global atomic, then coalesced agent-scope stores ----
    __syncthreads();
    int m = lcnt < LBUF ? lcnt : LBUF;
    if (tid == 0 && m > 0) sbase = atomicAdd(cnt_p, m);
    __syncthreads();
    for (int i = tid; i < m; i += 320) {
        int slot = sbase + i;
        if (slot < SEGCAP)
            __hip_atomic_store(&seg_p[slot], lbuf[i],
                               __ATOMIC_RELAXED, __HIP_MEMORY_SCOPE_AGENT);
    }

    // ---- arrival: last block of this batch runs stage B ----
    // __syncthreads drains vmcnt(0): all agent-scope stores are at the
    // coherence point before the release add below.
    __syncthreads();
    if (tid == 0) {
        int prev = __hip_atomic_fetch_add(&g_arrive[b], 1,
                                          __ATOMIC_ACQ_REL, __HIP_MEMORY_SCOPE_AGENT);
        lastflag = (prev == BPB - 1);
    }
    __syncthreads();
    if (!lastflag) return;

    topk_stage(b, tid, dxy, swh, out);
}

extern "C" void kernel_launch(void* const* d_in, const int* in_sizes, int n_in,
                              void* d_out, int out_size, void* d_ws, size_t ws_size,
                              hipStream_t stream) {
    const float* cls = (const float*)d_in[0];
    const float* dxy = (const float*)d_in[1];
    const float* swh = (const float*)d_in[2];
    float* out = (float*)d_out;

    fused_kernel<<<NBLK, 320, 0, stream>>>(cls, dxy, swh, out);
}

// Round 6
// 173.190 us; speedup vs baseline: 1.2156x; 1.1957x over previous
//
#include <hip/hip_runtime.h>
#include <cstdint>

#define B 16
#define H 128
#define W 128
#define NC 80
#define PB (H*W*NC)
#define K 100
#define NSUB 16          // sub-counters per batch (atomic distribution)
#define SEGCAP 1024      // candidate slots per (batch, sub)
#define THRESH 0.95f
#define NBINS 4096
#define LISTCAP 512
#define LBUF 256         // per-block LDS candidate buffer (exp ~26/block)
#define TY 16            // output rows per wave-tile
#define OX 14            // output cols per wave-tile (16 loaded, 14 emitted)
#define YT (H/TY)        // 8
#define XT 10            // ceil(W/OX)
#define NBLK (B*YT*XT)   // 1280
#define BPB (YT*XT)      // blocks per batch = 80

__device__ unsigned long long g_cand[B * NSUB * SEGCAP];   // 2 MB
__device__ int g_counts[B * NSUB * 16] = {};  // 64B-strided; zeroed at load; topk re-zeros
__device__ int g_arrive[B] = {};              // per-batch arrival counters; topk re-zeros

__device__ __forceinline__ float sigmoidf(float x) {
    return 1.0f / (1.0f + expf(-x));
}
__device__ __forceinline__ float4 f4max2(float4 a, float4 b) {
    float4 r;
    r.x = fmaxf(a.x, b.x); r.y = fmaxf(a.y, b.y);
    r.z = fmaxf(a.z, b.z); r.w = fmaxf(a.w, b.w);
    return r;
}
__device__ __forceinline__ float4 shfl4(float4 v, int src) {
    float4 r;
    r.x = __shfl(v.x, src);
    r.y = __shfl(v.y, src);
    r.z = __shfl(v.z, src);
    r.w = __shfl(v.w, src);
    return r;
}

// Fused kernel (round 6: remove cache-wide fences).
// Rounds 1-5 post-mortem: duration was CONSTANT ~110-115us across VGPR
// 28/88/44 and 1-6 blocks/CU residency — the bottleneck was never regalloc.
// It was the per-block ACQ_REL agent-scope fetch_add: on multi-XCD gfx950
// the release/acquire fences compile to buffer_wbl2/buffer_inv (cache-wide
// L2 writeback+invalidate). 1280 blocks / 8 XCDs = 160 serialized L2 flushes
// per XCD ~= 110us. Fix: NO fences anywhere. All cross-block communication
// uses RELAXED SYSTEM-scope atomic accesses (sc0 sc1: write-through to / read
// from the common coherence point, bypassing the non-coherent per-XCD L2s).
// Producer ordering: __syncthreads() drains vmcnt(0) per wave, so all
// write-through stores are at MALL before the arrival tick. Consumer reads
// bypass L1+L2 so they observe MALL directly. No XCD-placement assumptions.
// Regalloc: keep round-2's waves_per_eu(2,2) — proven 88 VGPR, pipeline
// intact; 1 block/CU keeps 5 waves x 7 float4 loads = 35KB/CU in flight,
// ample for HBM saturation.
__global__ void
__attribute__((amdgpu_flat_work_group_size(320, 320)))
__attribute__((amdgpu_waves_per_eu(2, 2)))
fused_kernel(const float* __restrict__ cls,
             const float* __restrict__ dxy,
             const float* __restrict__ swh,
             float* __restrict__ out) {
    const int raw = blockIdx.x;                          // 1280
    const int blk = (raw & 7) * (NBLK / 8) + (raw >> 3); // XCD-contiguous ranges
    const int b   = blk / (YT * XT);
    const int rem = blk - b * (YT * XT);
    const int yt  = rem / XT;
    const int xt  = rem - yt * XT;
    const int sub = rem & (NSUB - 1);                    // 16-way atomic distribution
    const int tid  = threadIdx.x;
    const int lane = tid & 63;
    const int cg   = tid >> 6;                           // class group 0..4
    const int c4   = lane & 3;
    const int xl   = lane >> 2;                          // 0..15
    const int xg   = xt * OX - 1 + xl;                   // global col, may be OOB
    const int y0   = yt * TY;
    const int cbase = cg * 16 + c4 * 4;

    __shared__ unsigned long long lbuf[LBUF];
    __shared__ int lcnt;
    __shared__ int sbase;
    __shared__ int lastflag;
    if (tid == 0) lcnt = 0;
    __syncthreads();

    int* const cnt_p = &g_counts[(b * NSUB + sub) * 16];
    unsigned long long* const seg_p = &g_cand[(size_t)(b * NSUB + sub) * SEGCAP];

    const float NI = -__builtin_inff();
    const float4 NEG = make_float4(NI, NI, NI, NI);
    const float* bp = cls + (size_t)b * PB + cbase;

    const bool xv = (xg >= 0) & (xg < W);
    const bool emitOK = (xl >= 1) & (xl <= OX) & (xg < W);

    const int lsrcL = (lane - 4) & 63;
    const int lsrcR = (lane + 4) & 63;

    auto ld = [&](int j) -> float4 {                     // raw row j (y = y0-1+j)
        const int y = y0 - 1 + j;
        const bool ok = (y >= 0) & (y < H) & xv;
        return ok ? *(const float4*)(bp + (size_t)(y * W + xg) * NC) : NEG;
    };

    // 8 named slots; rows 0..6 preloaded -> 7 loads in flight steady-state.
    float4 w0 = ld(0), w1 = ld(1), w2 = ld(2), w3 = ld(3);
    float4 w4 = ld(4), w5 = ld(5), w6 = ld(6), w7;

    float4 pair = f4max2(w0, w1);                        // max(rows k, k+1)

    auto step = [&](const float4& ctr, const float4& bot, float4& fre, int k) {
        if (k + 7 <= TY + 1) fre = ld(k + 7);            // prefetch row k+7
        float4 v3 = f4max2(pair, bot);                   // vertical 3-max, own col
        float cmax = fmaxf(fmaxf(ctr.x, ctr.y), fmaxf(ctr.z, ctr.w));
        const bool pre = emitOK & (cmax > 2.9f);         // candidate needs own v>2.9
        if (__any(pre)) {                                // wave-uniform skip
            float4 Lv = shfl4(v3, lsrcL);
            float4 Rv = shfl4(v3, lsrcR);
            float4 vm4 = f4max2(f4max2(Lv, Rv), v3);     // full 3x3 max (exact)
            if (pre) {
                const int yo = y0 + k;
                float vv[4] = { ctr.x, ctr.y, ctr.z, ctr.w };
                float mm[4] = { vm4.x, vm4.y, vm4.z, vm4.w };
                #pragma unroll
                for (int c = 0; c < 4; ++c) {
                    float v = vv[c], vm = mm[c];
                    // logit prefilter band 1e-3 >> worst-case sigmoid
                    // rounding-collision window (~1.5e-5)
                    if (v > 2.9f && (vm - v) <= 1e-3f) {
                        float sc = sigmoidf(v);
                        float sm = sigmoidf(vm);         // monotone: = max sigmoid
                        if (sc == sm && sc > THRESH) {
                            unsigned ib = ((unsigned)(yo * W + xg)) * NC + cbase + c;
                            unsigned long long key =
                                ((unsigned long long)__float_as_uint(sc) << 32) |
                                (unsigned long long)(0xFFFFFFFFu - ib);
                            int p = atomicAdd(&lcnt, 1);     // LDS atomic (lgkm)
                            if (p < LBUF) lbuf[p] = key;     // LDS write (lgkm)
                        }
                    }
                }
            }
        }
        pair = f4max2(ctr, bot);                         // pair for next step
    };

    // step k: ctr=row k+1 (slot (k+1)&7), bot=row k+2, fill slot (k+7)&7.
    step(w1, w2, w7, 0);   step(w2, w3, w0, 1);   step(w3, w4, w1, 2);
    step(w4, w5, w2, 3);   step(w5, w6, w3, 4);   step(w6, w7, w4, 5);
    step(w7, w0, w5, 6);   step(w0, w1, w6, 7);   step(w1, w2, w7, 8);
    step(w2, w3, w0, 9);   step(w3, w4, w1, 10);  step(w4, w5, w2, 11);
    step(w5, w6, w3, 12);  step(w6, w7, w4, 13);  step(w7, w0, w5, 14);
    step(w0, w1, w6, 15);

    // ---- block flush: ONE system-scope atomic, then write-through stores ----
    __syncthreads();
    int m = lcnt < LBUF ? lcnt : LBUF;
    if (tid == 0 && m > 0)
        sbase = __hip_atomic_fetch_add(cnt_p, m,
                                       __ATOMIC_RELAXED, __HIP_MEMORY_SCOPE_SYSTEM);
    __syncthreads();
    for (int i = tid; i < m; i += 320) {
        int slot = sbase + i;
        if (slot < SEGCAP)
            __hip_atomic_store(&seg_p[slot], lbuf[i],
                               __ATOMIC_RELAXED, __HIP_MEMORY_SCOPE_SYSTEM);
    }

    // ---- arrival: last block of this batch runs stage B ----
    // __syncthreads emits s_waitcnt vmcnt(0) per wave before s_barrier, so
    // every wave's write-through stores have completed at the coherence
    // point before any wave proceeds; tid0's RELAXED SYSTEM fetch_add then
    // cannot be observed before the data. No cache-wide fence needed.
    __syncthreads();
    if (tid == 0) {
        int prev = __hip_atomic_fetch_add(&g_arrive[b], 1,
                                          __ATOMIC_RELAXED, __HIP_MEMORY_SCOPE_SYSTEM);
        lastflag = (prev == BPB - 1);
    }
    __syncthreads();
    if (!lastflag) return;

    // ================= Stage B: exact top-K for batch b =================
    __shared__ int hist[NBINS];
    __shared__ int csum[256];
    __shared__ int segn[NSUB];
    __shared__ unsigned long long list[LISTCAP];
    __shared__ int lcount;
    __shared__ int kstar;

    if (tid < NSUB) {
        int n = __hip_atomic_load(&g_counts[(b * NSUB + tid) * 16],
                                  __ATOMIC_RELAXED, __HIP_MEMORY_SCOPE_SYSTEM);
        segn[tid] = n > SEGCAP ? SEGCAP : n;
    }
    for (int i = tid; i < NBINS; i += 320) hist[i] = 0;
    if (tid == 0) lcount = 0;
    __syncthreads();

    const float SCALE = (float)NBINS / (1.0f - THRESH);
    #pragma unroll 1
    for (int s = 0; s < NSUB; ++s) {
        unsigned long long* cb = g_cand + (size_t)(b * NSUB + s) * SEGCAP;
        const int n = segn[s];
        for (int i = tid; i < n; i += 320) {
            unsigned long long key = __hip_atomic_load(&cb[i],
                                     __ATOMIC_RELAXED, __HIP_MEMORY_SCOPE_SYSTEM);
            float v = __uint_as_float((unsigned)(key >> 32));
            int bin = (int)((v - THRESH) * SCALE);
            bin = bin < 0 ? 0 : (bin > NBINS - 1 ? NBINS - 1 : bin);
            atomicAdd(&hist[bin], 1);
        }
    }
    __syncthreads();

    if (tid < 256) {
        int s0 = 0;
        for (int j = 0; j < NBINS / 256; j++) s0 += hist[tid * (NBINS / 256) + j];
        csum[tid] = s0;
    }
    __syncthreads();

    if (tid == 0) {
        int acc = 0;
        int chunk = 255;
        for (; chunk >= 0; chunk--) {
            if (acc + csum[chunk] >= K) break;
            acc += csum[chunk];
        }
        int ks = 0;
        if (chunk >= 0) {
            int j = NBINS / 256 - 1;
            for (; j >= 0; j--) {
                acc += hist[chunk * (NBINS / 256) + j];
                if (acc >= K) break;
            }
            if (j < 0) j = 0;
            ks = chunk * (NBINS / 256) + j;
        }
        kstar = ks;
    }
    __syncthreads();

    const int ks = kstar;
    #pragma unroll 1
    for (int s = 0; s < NSUB; ++s) {
        unsigned long long* cb = g_cand + (size_t)(b * NSUB + s) * SEGCAP;
        const int n = segn[s];
        for (int i = tid; i < n; i += 320) {
            unsigned long long key = __hip_atomic_load(&cb[i],
                                     __ATOMIC_RELAXED, __HIP_MEMORY_SCOPE_SYSTEM);
            float v = __uint_as_float((unsigned)(key >> 32));
            int bin = (int)((v - THRESH) * SCALE);
            bin = bin < 0 ? 0 : (bin > NBINS - 1 ? NBINS - 1 : bin);
            if (bin >= ks) {
                int p = atomicAdd(&lcount, 1);
                if (p < LISTCAP) list[p] = key;
            }
        }
    }
    __syncthreads();
    const int M = lcount < LISTCAP ? lcount : LISTCAP;

    // exact rank by counting (keys distinct: low 32 bits unique per batch)
    for (int i = tid; i < M; i += 320) {
        unsigned long long key = list[i];
        int rank = 0;
        for (int j = 0; j < M; j++) rank += (list[j] > key);
        if (rank < K) {
            float conf = __uint_as_float((unsigned)(key >> 32));
            unsigned ib = 0xFFFFFFFFu - (unsigned)(key & 0xFFFFFFFFu);
            unsigned cls_i = ib % (unsigned)NC;
            unsigned sidx = ib / (unsigned)NC;
            unsigned xq = sidx & (W - 1);
            unsigned yq = sidx >> 7;

            size_t goff = ((size_t)b * (H * W) + sidx) * 2;
            float dx = dxy[goff], dy = dxy[goff + 1];
            float sw = swh[goff], sh = swh[goff + 1];

            float xs = (float)xq + dx;
            float ys = (float)yq + dy;
            float hw = sw * 0.5f;
            float hh = sh * 0.5f;
            const float invW = 1.0f / (float)W;
            const float invH = 1.0f / (float)H;

            int r = b * K + rank;
            out[r * 4 + 0] = (xs - hw) * invW;
            out[r * 4 + 1] = (ys - hh) * invH;
            out[r * 4 + 2] = (xs + hw) * invW;
            out[r * 4 + 3] = (ys + hh) * invH;
            out[B * K * 4 + r] = conf;
            out[B * K * 4 + B * K + r] = (float)cls_i;
        }
    }

    __syncthreads();
    // reset persistent state for the next call (system-scope so next
    // iteration's MALL-routed RMWs observe the zeros)
    if (tid < NSUB)
        __hip_atomic_store(&g_counts[(b * NSUB + tid) * 16], 0,
                           __ATOMIC_RELAXED, __HIP_MEMORY_SCOPE_SYSTEM);
    if (tid == 0)
        __hip_atomic_store(&g_arrive[b], 0,
                           __ATOMIC_RELAXED, __HIP_MEMORY_SCOPE_SYSTEM);
}

extern "C" void kernel_launch(void* const* d_in, const int* in_sizes, int n_in,
                              void* d_out, int out_size, void* d_ws, size_t ws_size,
                              hipStream_t stream) {
    const float* cls = (const float*)d_in[0];
    const float* dxy = (const float*)d_in[1];
    const float* swh = (const float*)d_in[2];
    float* out = (float*)d_out;

    fused_kernel<<<NBLK, 320, 0, stream>>>(cls, dxy, swh, out);
}

// Round 8
// 152.269 us; speedup vs baseline: 1.3826x; 1.1374x over previous
//
#include <hip/hip_runtime.h>
#include <cstdint>

#define B 16
#define H 128
#define W 128
#define NC 80
#define PB (H*W*NC)
#define K 100
#define NSUB 16          // sub-counters per batch (atomic distribution)
#define SEGCAP 1024      // candidate slots per (batch, sub)
#define THRESH 0.95f
#define NBINS 1024       // r7: 4096->1024. hist 16KB->4KB; cutoff coarser but
                         // final selection is exact rank-by-count, so only
                         // effect is a few more ties collected into list[]
#define LISTCAP 512
#define LBUF 256         // per-block LDS candidate buffer (exp ~26/block)
#define TY 16            // output rows per wave-tile
#define OX 14            // output cols per wave-tile (16 loaded, 14 emitted)
#define YT (H/TY)        // 8
#define XT 10            // ceil(W/OX)
#define NBLK (B*YT*XT)   // 1280
#define BPB (YT*XT)      // blocks per batch = 80

__device__ unsigned long long g_cand[B * NSUB * SEGCAP];   // 2 MB
__device__ int g_counts[B * NSUB * 16] = {};  // 64B-strided; zeroed at load; topk re-zeros
__device__ int g_arrive[B] = {};              // per-batch arrival counters; topk re-zeros

__device__ __forceinline__ float sigmoidf(float x) {
    return 1.0f / (1.0f + expf(-x));
}
__device__ __forceinline__ float4 f4max2(float4 a, float4 b) {
    float4 r;
    r.x = fmaxf(a.x, b.x); r.y = fmaxf(a.y, b.y);
    r.z = fmaxf(a.z, b.z); r.w = fmaxf(a.w, b.w);
    return r;
}
__device__ __forceinline__ float4 shfl4(float4 v, int src) {
    float4 r;
    r.x = __shfl(v.x, src);
    r.y = __shfl(v.y, src);
    r.z = __shfl(v.z, src);
    r.w = __shfl(v.w, src);
    return r;
}

// Fused kernel, round 8 == round 7 resubmit (round-7 bench was an infra
// failure; identical source, same prediction).
// RESIDENCY via small LDS, not attribute games.
// Cross-round evidence: VGPR 28/44/88 never changed runtime; what changed it
// was (a) the ACQ_REL cache-wide fences (removed in r6: 115->82us) and
// (b) blocks/CU. Round-0's fast stage A ran ~6 blocks/CU (30 waves) — TLP
// alone hides load latency even with the register pipeline sunk. Stage B's
// 24KB LDS (hist[4096]=16KB) was what crushed residency. Shrink NBINS to
// 1024: total LDS ~11.3KB -> 6 blocks/CU (wave-limited). Grid (1280 blocks)
// becomes ~fully resident. Plain launch_bounds like round-0; fence-free
// SYSTEM-scope relaxed atomics from round-6 kept verbatim.
__global__ __launch_bounds__(320, 2) void fused_kernel(const float* __restrict__ cls,
                                                       const float* __restrict__ dxy,
                                                       const float* __restrict__ swh,
                                                       float* __restrict__ out) {
    const int raw = blockIdx.x;                          // 1280
    const int blk = (raw & 7) * (NBLK / 8) + (raw >> 3); // XCD-contiguous ranges
    const int b   = blk / (YT * XT);
    const int rem = blk - b * (YT * XT);
    const int yt  = rem / XT;
    const int xt  = rem - yt * XT;
    const int sub = rem & (NSUB - 1);                    // 16-way atomic distribution
    const int tid  = threadIdx.x;
    const int lane = tid & 63;
    const int cg   = tid >> 6;                           // class group 0..4
    const int c4   = lane & 3;
    const int xl   = lane >> 2;                          // 0..15
    const int xg   = xt * OX - 1 + xl;                   // global col, may be OOB
    const int y0   = yt * TY;
    const int cbase = cg * 16 + c4 * 4;

    __shared__ unsigned long long lbuf[LBUF];
    __shared__ int lcnt;
    __shared__ int sbase;
    __shared__ int lastflag;
    if (tid == 0) lcnt = 0;
    __syncthreads();

    int* const cnt_p = &g_counts[(b * NSUB + sub) * 16];
    unsigned long long* const seg_p = &g_cand[(size_t)(b * NSUB + sub) * SEGCAP];

    const float NI = -__builtin_inff();
    const float4 NEG = make_float4(NI, NI, NI, NI);
    const float* bp = cls + (size_t)b * PB + cbase;

    const bool xv = (xg >= 0) & (xg < W);
    const bool emitOK = (xl >= 1) & (xl <= OX) & (xg < W);

    const int lsrcL = (lane - 4) & 63;
    const int lsrcR = (lane + 4) & 63;

    auto ld = [&](int j) -> float4 {                     // raw row j (y = y0-1+j)
        const int y = y0 - 1 + j;
        const bool ok = (y >= 0) & (y < H) & xv;
        return ok ? *(const float4*)(bp + (size_t)(y * W + xg) * NC) : NEG;
    };

    // 8 named slots; rows 0..6 preloaded -> 7 loads in flight steady-state.
    float4 w0 = ld(0), w1 = ld(1), w2 = ld(2), w3 = ld(3);
    float4 w4 = ld(4), w5 = ld(5), w6 = ld(6), w7;

    float4 pair = f4max2(w0, w1);                        // max(rows k, k+1)

    auto step = [&](const float4& ctr, const float4& bot, float4& fre, int k) {
        if (k + 7 <= TY + 1) fre = ld(k + 7);            // prefetch row k+7
        float4 v3 = f4max2(pair, bot);                   // vertical 3-max, own col
        float cmax = fmaxf(fmaxf(ctr.x, ctr.y), fmaxf(ctr.z, ctr.w));
        const bool pre = emitOK & (cmax > 2.9f);         // candidate needs own v>2.9
        if (__any(pre)) {                                // wave-uniform skip
            float4 Lv = shfl4(v3, lsrcL);
            float4 Rv = shfl4(v3, lsrcR);
            float4 vm4 = f4max2(f4max2(Lv, Rv), v3);     // full 3x3 max (exact)
            if (pre) {
                const int yo = y0 + k;
                float vv[4] = { ctr.x, ctr.y, ctr.z, ctr.w };
                float mm[4] = { vm4.x, vm4.y, vm4.z, vm4.w };
                #pragma unroll
                for (int c = 0; c < 4; ++c) {
                    float v = vv[c], vm = mm[c];
                    // logit prefilter band 1e-3 >> worst-case sigmoid
                    // rounding-collision window (~1.5e-5)
                    if (v > 2.9f && (vm - v) <= 1e-3f) {
                        float sc = sigmoidf(v);
                        float sm = sigmoidf(vm);         // monotone: = max sigmoid
                        if (sc == sm && sc > THRESH) {
                            unsigned ib = ((unsigned)(yo * W + xg)) * NC + cbase + c;
                            unsigned long long key =
                                ((unsigned long long)__float_as_uint(sc) << 32) |
                                (unsigned long long)(0xFFFFFFFFu - ib);
                            int p = atomicAdd(&lcnt, 1);     // LDS atomic (lgkm)
                            if (p < LBUF) lbuf[p] = key;     // LDS write (lgkm)
                        }
                    }
                }
            }
        }
        pair = f4max2(ctr, bot);                         // pair for next step
    };

    // step k: ctr=row k+1 (slot (k+1)&7), bot=row k+2, fill slot (k+7)&7.
    step(w1, w2, w7, 0);   step(w2, w3, w0, 1);   step(w3, w4, w1, 2);
    step(w4, w5, w2, 3);   step(w5, w6, w3, 4);   step(w6, w7, w4, 5);
    step(w7, w0, w5, 6);   step(w0, w1, w6, 7);   step(w1, w2, w7, 8);
    step(w2, w3, w0, 9);   step(w3, w4, w1, 10);  step(w4, w5, w2, 11);
    step(w5, w6, w3, 12);  step(w6, w7, w4, 13);  step(w7, w0, w5, 14);
    step(w0, w1, w6, 15);

    // ---- block flush: ONE system-scope atomic, then write-through stores ----
    __syncthreads();
    int m = lcnt < LBUF ? lcnt : LBUF;
    if (tid == 0 && m > 0)
        sbase = __hip_atomic_fetch_add(cnt_p, m,
                                       __ATOMIC_RELAXED, __HIP_MEMORY_SCOPE_SYSTEM);
    __syncthreads();
    for (int i = tid; i < m; i += 320) {
        int slot = sbase + i;
        if (slot < SEGCAP)
            __hip_atomic_store(&seg_p[slot], lbuf[i],
                               __ATOMIC_RELAXED, __HIP_MEMORY_SCOPE_SYSTEM);
    }

    // ---- arrival: last block of this batch runs stage B ----
    // __syncthreads emits s_waitcnt vmcnt(0) per wave before s_barrier, so
    // every wave's write-through stores have completed at the coherence
    // point before tid0's RELAXED SYSTEM fetch_add. No cache-wide fence.
    __syncthreads();
    if (tid == 0) {
        int prev = __hip_atomic_fetch_add(&g_arrive[b], 1,
                                          __ATOMIC_RELAXED, __HIP_MEMORY_SCOPE_SYSTEM);
        lastflag = (prev == BPB - 1);
    }
    __syncthreads();
    if (!lastflag) return;

    // ================= Stage B: exact top-K for batch b =================
    __shared__ int hist[NBINS];
    __shared__ int csum[256];
    __shared__ int segn[NSUB];
    __shared__ unsigned long long list[LISTCAP];
    __shared__ int lcount;
    __shared__ int kstar;

    if (tid < NSUB) {
        int n = __hip_atomic_load(&g_counts[(b * NSUB + tid) * 16],
                                  __ATOMIC_RELAXED, __HIP_MEMORY_SCOPE_SYSTEM);
        segn[tid] = n > SEGCAP ? SEGCAP : n;
    }
    for (int i = tid; i < NBINS; i += 320) hist[i] = 0;
    if (tid == 0) lcount = 0;
    __syncthreads();

    const float SCALE = (float)NBINS / (1.0f - THRESH);
    #pragma unroll 1
    for (int s = 0; s < NSUB; ++s) {
        unsigned long long* cb = g_cand + (size_t)(b * NSUB + s) * SEGCAP;
        const int n = segn[s];
        for (int i = tid; i < n; i += 320) {
            unsigned long long key = __hip_atomic_load(&cb[i],
                                     __ATOMIC_RELAXED, __HIP_MEMORY_SCOPE_SYSTEM);
            float v = __uint_as_float((unsigned)(key >> 32));
            int bin = (int)((v - THRESH) * SCALE);
            bin = bin < 0 ? 0 : (bin > NBINS - 1 ? NBINS - 1 : bin);
            atomicAdd(&hist[bin], 1);
        }
    }
    __syncthreads();

    if (tid < 256) {
        int s0 = 0;
        for (int j = 0; j < NBINS / 256; j++) s0 += hist[tid * (NBINS / 256) + j];
        csum[tid] = s0;
    }
    __syncthreads();

    if (tid == 0) {
        int acc = 0;
        int chunk = 255;
        for (; chunk >= 0; chunk--) {
            if (acc + csum[chunk] >= K) break;
            acc += csum[chunk];
        }
        int ks = 0;
        if (chunk >= 0) {
            int j = NBINS / 256 - 1;
            for (; j >= 0; j--) {
                acc += hist[chunk * (NBINS / 256) + j];
                if (acc >= K) break;
            }
            if (j < 0) j = 0;
            ks = chunk * (NBINS / 256) + j;
        }
        kstar = ks;
    }
    __syncthreads();

    const int ks = kstar;
    #pragma unroll 1
    for (int s = 0; s < NSUB; ++s) {
        unsigned long long* cb = g_cand + (size_t)(b * NSUB + s) * SEGCAP;
        const int n = segn[s];
        for (int i = tid; i < n; i += 320) {
            unsigned long long key = __hip_atomic_load(&cb[i],
                                     __ATOMIC_RELAXED, __HIP_MEMORY_SCOPE_SYSTEM);
            float v = __uint_as_float((unsigned)(key >> 32));
            int bin = (int)((v - THRESH) * SCALE);
            bin = bin < 0 ? 0 : (bin > NBINS - 1 ? NBINS - 1 : bin);
            if (bin >= ks) {
                int p = atomicAdd(&lcount, 1);
                if (p < LISTCAP) list[p] = key;
            }
        }
    }
    __syncthreads();
    const int M = lcount < LISTCAP ? lcount : LISTCAP;

    // exact rank by counting (keys distinct: low 32 bits unique per batch)
    for (int i = tid; i < M; i += 320) {
        unsigned long long key = list[i];
        int rank = 0;
        for (int j = 0; j < M; j++) rank += (list[j] > key);
        if (rank < K) {
            float conf = __uint_as_float((unsigned)(key >> 32));
            unsigned ib = 0xFFFFFFFFu - (unsigned)(key & 0xFFFFFFFFu);
            unsigned cls_i = ib % (unsigned)NC;
            unsigned sidx = ib / (unsigned)NC;
            unsigned xq = sidx & (W - 1);
            unsigned yq = sidx >> 7;

            size_t goff = ((size_t)b * (H * W) + sidx) * 2;
            float dx = dxy[goff], dy = dxy[goff + 1];
            float sw = swh[goff], sh = swh[goff + 1];

            float xs = (float)xq + dx;
            float ys = (float)yq + dy;
            float hw = sw * 0.5f;
            float hh = sh * 0.5f;
            const float invW = 1.0f / (float)W;
            const float invH = 1.0f / (float)H;

            int r = b * K + rank;
            out[r * 4 + 0] = (xs - hw) * invW;
            out[r * 4 + 1] = (ys - hh) * invH;
            out[r * 4 + 2] = (xs + hw) * invW;
            out[r * 4 + 3] = (ys + hh) * invH;
            out[B * K * 4 + r] = conf;
            out[B * K * 4 + B * K + r] = (float)cls_i;
        }
    }

    __syncthreads();
    // reset persistent state for the next call (system-scope so next
    // iteration's MALL-routed RMWs observe the zeros)
    if (tid < NSUB)
        __hip_atomic_store(&g_counts[(b * NSUB + tid) * 16], 0,
                           __ATOMIC_RELAXED, __HIP_MEMORY_SCOPE_SYSTEM);
    if (tid == 0)
        __hip_atomic_store(&g_arrive[b], 0,
                           __ATOMIC_RELAXED, __HIP_MEMORY_SCOPE_SYSTEM);
}

extern "C" void kernel_launch(void* const* d_in, const int* in_sizes, int n_in,
                              void* d_out, int out_size, void* d_ws, size_t ws_size,
                              hipStream_t stream) {
    const float* cls = (const float*)d_in[0];
    const float* dxy = (const float*)d_in[1];
    const float* swh = (const float*)d_in[2];
    float* out = (float*)d_out;

    fused_kernel<<<NBLK, 320, 0, stream>>>(cls, dxy, swh, out);
}